// Round 11
// baseline (635.649 us; speedup 1.0000x reference)
//
#include <hip/hip_runtime.h>
#include <hip/hip_bf16.h>

#define K_DIM 4096
#define N_DIM 4096
#define M_DIM 8192
#define PW_COLS 1024  // K_DIM/4

typedef __attribute__((ext_vector_type(4))) float f32x4;
typedef __attribute__((ext_vector_type(8))) short bf16x8;
typedef __attribute__((address_space(3))) void lds_void_t;
typedef __attribute__((address_space(1))) const void glb_void_t;

__device__ __forceinline__ unsigned short f2bf(float f) {
    unsigned int u = __float_as_uint(f);
    u += 0x7FFF + ((u >> 16) & 1);   // round-to-nearest-even
    return (unsigned short)(u >> 16);
}

// ternary code {0,1,2,3} -> bf16 bits of {-1,0,1,2}
__device__ __forceinline__ unsigned short wlut(int tt) {
    return (unsigned short)(0x40003F800000BF80ULL >> (tt << 4));
}

// ---------------- pre-pass 1: x fp32 -> bf16 ----------------
__global__ __launch_bounds__(256)
void convert_x_kernel(const float* __restrict__ x, unsigned short* __restrict__ xb, int n8)
{
    int stride = gridDim.x * blockDim.x;
    for (int i = blockIdx.x * blockDim.x + threadIdx.x; i < n8; i += stride) {
        float4 v0 = *(const float4*)(x + (size_t)i * 8);
        float4 v1 = *(const float4*)(x + (size_t)i * 8 + 4);
        ushort4 o0, o1;
        o0.x = f2bf(v0.x); o0.y = f2bf(v0.y); o0.z = f2bf(v0.z); o0.w = f2bf(v0.w);
        o1.x = f2bf(v1.x); o1.y = f2bf(v1.y); o1.z = f2bf(v1.z); o1.w = f2bf(v1.w);
        *(ushort4*)(xb + (size_t)i * 8) = o0;
        *(ushort4*)(xb + (size_t)i * 8 + 4) = o1;
    }
}

// ---------------- pre-pass 2: pw -> bf16 W [N][K] ----------------
__global__ __launch_bounds__(256)
void unpack_w_kernel(const int* __restrict__ pw, unsigned short* __restrict__ wb, int n2)
{
    int stride = gridDim.x * blockDim.x;
    for (int i = blockIdx.x * blockDim.x + threadIdx.x; i < n2; i += stride) {
        int2 p = *(const int2*)(pw + (size_t)i * 2);
        ushort4 a, b;
        a.x = wlut( p.x       & 3);
        a.y = wlut((p.x >> 2) & 3);
        a.z = wlut((p.x >> 4) & 3);
        a.w = wlut((p.x >> 6) & 3);
        b.x = wlut( p.y       & 3);
        b.y = wlut((p.y >> 2) & 3);
        b.z = wlut((p.y >> 4) & 3);
        b.w = wlut((p.y >> 6) & 3);
        *(ushort4*)(wb + (size_t)i * 8) = a;
        *(ushort4*)(wb + (size_t)i * 8 + 4) = b;
    }
}

// ---------------- main GEMM: 256x256, B in LDS (r5 schedule), A direct from global ----------------
#define BM 256
#define BN 256
#define BK 64
#define GTHREADS 512
#define BUF_BYTES 32768   // B only: 256 rows x 64 cols x 2B
#define HALF 16384        // one 128-row half of the B tile
#define NTILES 64         // K_DIM / BK

#define BARRIER() asm volatile("s_barrier" ::: "memory")
#define VMCNT(N)  asm volatile("s_waitcnt vmcnt(" #N ")" ::: "memory")
#define LGKM0()   asm volatile("s_waitcnt lgkmcnt(0)" ::: "memory")

// MFMA quadrant: 16 MFMAs, kk-outer (8 independent per kk; acc dep distance 8)
#define MMQ(Aarr, Barr, MH, NH) do { \
    __builtin_amdgcn_s_setprio(1); \
    _Pragma("unroll") \
    for (int kk = 0; kk < 2; ++kk) { \
      _Pragma("unroll") \
      for (int im = 0; im < 4; ++im) { \
        _Pragma("unroll") \
        for (int jn = 0; jn < 2; ++jn) { \
          acc[MH][im][NH][jn] = __builtin_amdgcn_mfma_f32_16x16x32_bf16( \
              Aarr[im][kk], Barr[jn][kk], acc[MH][im][NH][jn], 0, 0, 0); \
        } \
      } \
    } \
    __builtin_amdgcn_s_setprio(0); \
} while (0)

__global__ __launch_bounds__(GTHREADS, 2)
void gemm_adirect(const unsigned short* __restrict__ A,   // [M][K] bf16
                  const unsigned short* __restrict__ B,   // [N][K] bf16
                  const float* __restrict__ scale,
                  const float* __restrict__ bias,
                  float* __restrict__ out)
{
    extern __shared__ __align__(16) char smem[];

    const int t    = threadIdx.x;
    const int lane = t & 63;
    const int wave = t >> 6;
    const int wm = wave >> 2;      // 0..1  (M group)
    const int wn = wave & 3;       // 0..3  (N group)
    const int lr = lane & 15;
    const int lk = lane >> 4;      // 0..3

    // bijective XCD swizzle: 512 blocks, 8 XCDs, 64 per chunk
    int bid = blockIdx.x;
    int swz = (bid & 7) * 64 + (bid >> 3);
    const int m0 = (swz >> 4) * BM;   // 32 m-blocks
    const int n0 = (swz & 15) * BN;   // 16 n-blocks

    // ---- B staging (pre-swizzled global source, linear LDS dest) — r5-verified ----
    const int l8 = lane >> 3;                 // 0..7
    const int lc = ((lane & 7) ^ l8) * 8;     // inverse-swizzled col (elems)
    const unsigned short* bS = B + (size_t)(n0 + wave * 16 + l8) * K_DIM + lc;
    char* const lds0 = smem;
    char* const lds1 = smem + BUF_BYTES;
    const int chunkoff = wave * 2048;

    auto stageB = [&](char* buf, int h, int kt) {
        const unsigned short* s0 = bS + (size_t)(h * 128) * K_DIM + kt;
        char* d0 = buf + h * HALF + chunkoff;
        __builtin_amdgcn_global_load_lds((glb_void_t*)s0,
            (lds_void_t*)(void*)d0, 16, 0, 0);
        __builtin_amdgcn_global_load_lds((glb_void_t*)(s0 + 8 * K_DIM),
            (lds_void_t*)(void*)(d0 + 1024), 16, 0, 0);
    };

    // ---- B fragment-read offsets (swizzled, r5-verified) ----
    const int swzc = (lr & 7) << 4;
    const int cx0 = (lk * 16) ^ swzc;         // kk=0 col bytes
    const int cx1 = (64 + lk * 16) ^ swzc;    // kk=1
    const int brow = (wn * 32 + lr) * 128;

    // ---- A direct-from-global fragment base (per-wave private, layout = fragment) ----
    const unsigned short* aG = A + (size_t)(m0 + wm * 64 + lr) * K_DIM + lk * 8;

    f32x4 acc[2][4][2][2] = {};   // [mh][im][nh][jn]
    bf16x8 a0[4][2], a1[4][2];    // A fragments [im][kk] for mh=0 / mh=1
    bf16x8 b0[2][2], b1[2][2];    // B fragments [jn][kk] for nh=0 / nh=1

    auto loadA = [&](bf16x8 (&dst)[4][2], int mh, int kt) {
#pragma unroll
        for (int im = 0; im < 4; ++im) {
            const unsigned short* p = aG + (size_t)(mh * 128 + im * 16) * K_DIM + kt;
#pragma unroll
            for (int kk = 0; kk < 2; ++kk)
                dst[im][kk] = *(const bf16x8*)(p + kk * 32);
        }
    };
    auto LDB = [&](bf16x8 (&dst)[2][2], const char* buf, int nh) {
#pragma unroll
        for (int jn = 0; jn < 2; ++jn) {
            const char* p = buf + nh * HALF + brow + jn * 2048;
            dst[jn][0] = *(const bf16x8*)(p + cx0);
            dst[jn][1] = *(const bf16x8*)(p + cx1);
        }
    };

    // ---- prologue (issue order mimics steady-state FIFO pattern) ----
    stageB(lds0, 0, 0);      // Bh0(t0) 2
    stageB(lds0, 1, 0);      // Bh1(t0) 2
    stageB(lds1, 0, BK);     // Bh0(t1) 2
    loadA(a0, 0, 0);         // a0(t0)  8
    stageB(lds1, 1, BK);     // Bh1(t1) 2
    loadA(a1, 1, 0);         // a1(t0)  8
    VMCNT(20);               // retire Bh0(t0)+Bh1(t0); leave [Bh0(t1),a0,Bh1(t1),a1]
    BARRIER();
    LDB(b0, lds0, 0);        // preread b0(t0)

    char* cur = lds0;
    char* nxt = lds1;
    for (int tt = 0; tt < NTILES; ++tt) {
        const int ktn = (tt + 1) * BK;
        const int kt2 = (tt + 2) * BK;
        const bool st = (tt < NTILES - 2);
        const bool rd = (tt < NTILES - 1);

        // ---- R1: read b1 <- cur.Bh1 ; MFMA Q(0,0) ----
        LDB(b1, cur, 1);
        MMQ(a0, b0, 0, 0);
        LGKM0();
        BARRIER();

        // ---- R2: stage Bh0(t+2) -> cur ; MFMA Q(0,1) ; GUARD ----
        if (st) stageB(cur, 0, kt2);
        MMQ(a0, b1, 0, 1);
        // retire through Bh1(t+1): guards R4's b0-read (2 barriers) and
        // next R1's b1-read (3 barriers). Ledger: leaves [a1(t)x8, Bh0(t+2)x2].
        if (st)      { VMCNT(10); }
        else if (rd) { VMCNT(8);  }
        else         { VMCNT(0);  }
        LGKM0();
        BARRIER();

        // ---- R3: load a0(t+1) from global ; stage Bh1(t+2) -> cur ; MFMA Q(1,1) ----
        if (rd) loadA(a0, 0, ktn);
        if (st) stageB(cur, 1, kt2);
        MMQ(a1, b1, 1, 1);
        LGKM0();
        BARRIER();

        // ---- R4: MFMA Q(1,0) ; load a1(t+1) ; read b0 <- nxt.Bh0(t+1) ----
        MMQ(a1, b0, 1, 0);
        if (rd) loadA(a1, 1, ktn);
        if (rd) LDB(b0, nxt, 0);
        LGKM0();
        BARRIER();

        char* tmp = cur; cur = nxt; nxt = tmp;
    }

    // ---- epilogue: scale/bias/clip, fp32 store ----
#pragma unroll
    for (int mh = 0; mh < 2; ++mh)
#pragma unroll
    for (int nh = 0; nh < 2; ++nh)
#pragma unroll
    for (int jn = 0; jn < 2; ++jn) {
        int gc = n0 + nh * 128 + wn * 32 + jn * 16 + lr;
        float sc = scale[gc];
        float bi = bias[gc];
#pragma unroll
        for (int im = 0; im < 4; ++im) {
            int gr = m0 + mh * 128 + wm * 64 + im * 16 + lk * 4;
#pragma unroll
            for (int v = 0; v < 4; ++v) {
                float val = acc[mh][im][nh][jn][v] * sc + bi;
                val = fminf(fmaxf(val, -100.0f), 100.0f);
                out[(size_t)(gr + v) * N_DIM + gc] = val;
            }
        }
    }
}

// ---------------- fallback: fused kernel (ws too small) ----------------
#define FBM 128
#define FBN 128
#define FBK 64

__global__ __launch_bounds__(256)
void ternary_mm_fused(const float* __restrict__ x,
                      const int* __restrict__ pw,
                      const float* __restrict__ scale,
                      const float* __restrict__ bias,
                      float* __restrict__ out)
{
    __shared__ unsigned char As[FBM * FBK * 2];
    __shared__ unsigned char Ws[FBN * FBK * 2];

    const int t    = threadIdx.x;
    const int lane = t & 63;
    const int wave = t >> 6;
    const int wr = wave >> 1;
    const int wc = wave & 1;
    const int lr = lane & 15;
    const int lk = lane >> 4;

    const int n0 = blockIdx.x * FBN;
    const int m0 = blockIdx.y * FBM;

    f32x4 acc[4][4];
#pragma unroll
    for (int m = 0; m < 4; ++m)
#pragma unroll
        for (int n = 0; n < 4; ++n)
            acc[m][n] = (f32x4){0.f, 0.f, 0.f, 0.f};

    for (int kt = 0; kt < K_DIM; kt += FBK) {
#pragma unroll
        for (int p = 0; p < 8; ++p) {
            int idx = p * 256 + t;
            int row = idx >> 4;
            int c4  = idx & 15;
            float4 v = *(const float4*)(x + (size_t)(m0 + row) * K_DIM + kt + c4 * 4);
            ushort4 o;
            o.x = f2bf(v.x); o.y = f2bf(v.y); o.z = f2bf(v.z); o.w = f2bf(v.w);
            int off = (row * 128 + c4 * 8) ^ ((row & 7) << 4);
            *(ushort4*)(As + off) = o;
        }
#pragma unroll
        for (int p = 0; p < 2; ++p) {
            int idx = p * 256 + t;
            int row = idx >> 2;
            int q   = idx & 3;
            int4 v = *(const int4*)(pw + (size_t)(n0 + row) * PW_COLS + (kt >> 2) + q * 4);
            int base = row * 128 + q * 32;
            int xr = (row & 7) << 4;
            int pv[4] = {v.x, v.y, v.z, v.w};
#pragma unroll
            for (int j = 0; j < 4; ++j) {
                ushort4 o;
                o.x = wlut( pv[j]       & 3);
                o.y = wlut((pv[j] >> 2) & 3);
                o.z = wlut((pv[j] >> 4) & 3);
                o.w = wlut((pv[j] >> 6) & 3);
                *(ushort4*)(Ws + ((base + j * 8) ^ xr)) = o;
            }
        }
        __syncthreads();

#pragma unroll
        for (int kk = 0; kk < 2; ++kk) {
            const int cb = kk * 64 + lk * 16;
            bf16x8 af[4], bw[4];
#pragma unroll
            for (int m = 0; m < 4; ++m) {
                int row = wr * 64 + m * 16 + lr;
                af[m] = *(const bf16x8*)(As + ((row * 128 + cb) ^ ((lr & 7) << 4)));
            }
#pragma unroll
            for (int n = 0; n < 4; ++n) {
                int row = wc * 64 + n * 16 + lr;
                bw[n] = *(const bf16x8*)(Ws + ((row * 128 + cb) ^ ((lr & 7) << 4)));
            }
#pragma unroll
            for (int m = 0; m < 4; ++m)
#pragma unroll
                for (int n = 0; n < 4; ++n)
                    acc[m][n] = __builtin_amdgcn_mfma_f32_16x16x32_bf16(
                        af[m], bw[n], acc[m][n], 0, 0, 0);
        }
        __syncthreads();
    }

#pragma unroll
    for (int n = 0; n < 4; ++n) {
        int gcol = n0 + wc * 64 + n * 16 + lr;
        float s = scale[gcol];
        float b = bias[gcol];
#pragma unroll
        for (int m = 0; m < 4; ++m) {
            int growb = m0 + wr * 64 + m * 16 + lk * 4;
#pragma unroll
            for (int r = 0; r < 4; ++r) {
                float v = acc[m][n][r] * s + b;
                v = fminf(fmaxf(v, -100.0f), 100.0f);
                out[(size_t)(growb + r) * N_DIM + gcol] = v;
            }
        }
    }
}

extern "C" void kernel_launch(void* const* d_in, const int* in_sizes, int n_in,
                              void* d_out, int out_size, void* d_ws, size_t ws_size,
                              hipStream_t stream) {
    const float* x     = (const float*)d_in[0];
    const int*   pw    = (const int*)d_in[1];
    const float* scale = (const float*)d_in[2];
    const float* bias  = (const float*)d_in[3];
    float* out = (float*)d_out;

    const size_t xb_bytes = (size_t)M_DIM * K_DIM * 2;
    const size_t wb_bytes = (size_t)N_DIM * K_DIM * 2;
    if (ws_size >= xb_bytes + wb_bytes) {
        unsigned short* xb = (unsigned short*)d_ws;
        unsigned short* wb = (unsigned short*)((char*)d_ws + xb_bytes);

        int n8 = (M_DIM * K_DIM) / 8;
        convert_x_kernel<<<2048, 256, 0, stream>>>(x, xb, n8);
        int n2 = (N_DIM * PW_COLS) / 2;
        unpack_w_kernel<<<2048, 256, 0, stream>>>(pw, wb, n2);

        (void)hipFuncSetAttribute(reinterpret_cast<const void*>(gemm_adirect),
                                  hipFuncAttributeMaxDynamicSharedMemorySize,
                                  2 * BUF_BYTES);
        dim3 grid((M_DIM / BM) * (N_DIM / BN));   // 512
        gemm_adirect<<<grid, GTHREADS, 2 * BUF_BYTES, stream>>>(xb, wb, scale, bias, out);
    } else {
        dim3 grid(N_DIM / FBN, M_DIM / FBM);
        ternary_mm_fused<<<grid, 256, 0, stream>>>(x, pw, scale, bias, out);
    }
}

// Round 12
// 305.492 us; speedup vs baseline: 2.0807x; 2.0807x over previous
//
#include <hip/hip_runtime.h>
#include <hip/hip_bf16.h>

#define K_DIM 4096
#define N_DIM 4096
#define M_DIM 8192
#define PW_COLS 1024  // K_DIM/4

typedef __attribute__((ext_vector_type(4))) float f32x4;
typedef __attribute__((ext_vector_type(16))) float f32x16;
typedef __attribute__((ext_vector_type(8))) short bf16x8;
typedef __attribute__((address_space(3))) void lds_void_t;
typedef __attribute__((address_space(1))) const void glb_void_t;

__device__ __forceinline__ unsigned short f2bf(float f) {
    unsigned int u = __float_as_uint(f);
    u += 0x7FFF + ((u >> 16) & 1);   // round-to-nearest-even
    return (unsigned short)(u >> 16);
}

// ternary code {0,1,2,3} -> bf16 bits of {-1,0,1,2}
__device__ __forceinline__ unsigned short wlut(int tt) {
    return (unsigned short)(0x40003F800000BF80ULL >> (tt << 4));
}

// ---------------- pre-pass 1: x fp32 -> bf16 ----------------
__global__ __launch_bounds__(256)
void convert_x_kernel(const float* __restrict__ x, unsigned short* __restrict__ xb, int n8)
{
    int stride = gridDim.x * blockDim.x;
    for (int i = blockIdx.x * blockDim.x + threadIdx.x; i < n8; i += stride) {
        float4 v0 = *(const float4*)(x + (size_t)i * 8);
        float4 v1 = *(const float4*)(x + (size_t)i * 8 + 4);
        ushort4 o0, o1;
        o0.x = f2bf(v0.x); o0.y = f2bf(v0.y); o0.z = f2bf(v0.z); o0.w = f2bf(v0.w);
        o1.x = f2bf(v1.x); o1.y = f2bf(v1.y); o1.z = f2bf(v1.z); o1.w = f2bf(v1.w);
        *(ushort4*)(xb + (size_t)i * 8) = o0;
        *(ushort4*)(xb + (size_t)i * 8 + 4) = o1;
    }
}

// ---------------- pre-pass 2: pw -> bf16 W [N][K] ----------------
__global__ __launch_bounds__(256)
void unpack_w_kernel(const int* __restrict__ pw, unsigned short* __restrict__ wb, int n2)
{
    int stride = gridDim.x * blockDim.x;
    for (int i = blockIdx.x * blockDim.x + threadIdx.x; i < n2; i += stride) {
        int2 p = *(const int2*)(pw + (size_t)i * 2);
        ushort4 a, b;
        a.x = wlut( p.x       & 3);
        a.y = wlut((p.x >> 2) & 3);
        a.z = wlut((p.x >> 4) & 3);
        a.w = wlut((p.x >> 6) & 3);
        b.x = wlut( p.y       & 3);
        b.y = wlut((p.y >> 2) & 3);
        b.z = wlut((p.y >> 4) & 3);
        b.w = wlut((p.y >> 6) & 3);
        *(ushort4*)(wb + (size_t)i * 8) = a;
        *(ushort4*)(wb + (size_t)i * 8 + 4) = b;
    }
}

// ---------------- main GEMM: r5 schedule, 32x32x16 MFMA ----------------
#define BM 256
#define BN 256
#define BK 64
#define GTHREADS 512
#define BUF_BYTES 65536   // A 32K + B 32K
#define B_TILE 32768
#define HALF 16384
#define NTILES 64         // K_DIM / BK

#define BARRIER() asm volatile("s_barrier" ::: "memory")
#define VMCNT(N)  asm volatile("s_waitcnt vmcnt(" #N ")" ::: "memory")

// MFMA quadrant: 8 MFMAs of 32x32x16 (ks-outer; 2 independent per ks)
#define MMQ32(Aarr, Barr, MH, NH) do { \
    __builtin_amdgcn_s_setprio(1); \
    _Pragma("unroll") \
    for (int ks = 0; ks < 4; ++ks) { \
      _Pragma("unroll") \
      for (int ms = 0; ms < 2; ++ms) { \
        acc[MH][ms][NH] = __builtin_amdgcn_mfma_f32_32x32x16_bf16( \
            Aarr[ms][ks], Barr[ks], acc[MH][ms][NH], 0, 0, 0); \
      } \
    } \
    __builtin_amdgcn_s_setprio(0); \
} while (0)

__global__ __launch_bounds__(GTHREADS, 2)
void gemm_3232(const unsigned short* __restrict__ A,   // [M][K] bf16
               const unsigned short* __restrict__ B,   // [N][K] bf16
               const float* __restrict__ scale,
               const float* __restrict__ bias,
               float* __restrict__ out)
{
    extern __shared__ __align__(16) char smem[];

    const int t    = threadIdx.x;
    const int lane = t & 63;
    const int wave = t >> 6;
    const int wm = wave >> 2;      // 0..1  (M group)
    const int wn = wave & 3;       // 0..3  (N group)
    const int l31 = lane & 31;     // row within 32-row subtile
    const int lh  = lane >> 5;     // 0..1  (k-half within K=16)

    // bijective XCD swizzle: 512 blocks, 8 XCDs, 64 per chunk
    int bid = blockIdx.x;
    int swz = (bid & 7) * 64 + (bid >> 3);
    const int m0 = (swz >> 4) * BM;   // 32 m-blocks
    const int n0 = (swz & 15) * BN;   // 16 n-blocks

    // ---- staging addresses (pre-swizzled global source, linear LDS dest) — r5-verified ----
    const int l8 = lane >> 3;                 // 0..7  (row within 8-row chunk)
    const int lc = ((lane & 7) ^ l8) * 8;     // inverse-swizzled col (elems)
    const unsigned short* aS = A + (size_t)(m0 + wave * 16 + l8) * K_DIM + lc;
    const unsigned short* bS = B + (size_t)(n0 + wave * 16 + l8) * K_DIM + lc;
    char* const lds0 = smem;
    char* const lds1 = smem + BUF_BYTES;
    const int chunkoff = wave * 2048;         // 2 chunks x 1024B per wave

    auto stageA = [&](char* buf, int h, int kt) {
        const unsigned short* s0 = aS + (size_t)(h * 128) * K_DIM + kt;
        char* d0 = buf + h * HALF + chunkoff;
        __builtin_amdgcn_global_load_lds((glb_void_t*)s0,
            (lds_void_t*)(void*)d0, 16, 0, 0);
        __builtin_amdgcn_global_load_lds((glb_void_t*)(s0 + 8 * K_DIM),
            (lds_void_t*)(void*)(d0 + 1024), 16, 0, 0);
    };
    auto stageB = [&](char* buf, int h, int kt) {
        const unsigned short* s0 = bS + (size_t)(h * 128) * K_DIM + kt;
        char* d0 = buf + B_TILE + h * HALF + chunkoff;
        __builtin_amdgcn_global_load_lds((glb_void_t*)s0,
            (lds_void_t*)(void*)d0, 16, 0, 0);
        __builtin_amdgcn_global_load_lds((glb_void_t*)(s0 + 8 * K_DIM),
            (lds_void_t*)(void*)(d0 + 1024), 16, 0, 0);
    };

    // ---- fragment-read offsets (swizzled; 32x32x16 operand layout) ----
    // A/B operand: lane holds row = lane&31, k = (lane>>5)*8 + j (8 contiguous, 16B)
    const int swz7 = (lane & 7) << 4;
    int cxk[4];
#pragma unroll
    for (int ks = 0; ks < 4; ++ks)
        cxk[ks] = (ks * 32 + lh * 16) ^ swz7;      // byte offset within 128B row
    const int arow = (wm * 64 + l31) * 128;        // + ms*32 rows -> +ms*4096
    const int brow = (wn * 32 + l31) * 128 + B_TILE;

    f32x16 acc[2][2][2] = {};     // [mh][ms][nh]
    bf16x8 a0[2][4], a1[2][4];    // A fragments [ms][ks] for mh=0 / mh=1
    bf16x8 b0[4], b1[4];          // B fragments [ks] for nh=0 / nh=1

    auto LDA = [&](bf16x8 (&dst)[2][4], const char* buf, int mh) {
#pragma unroll
        for (int ms = 0; ms < 2; ++ms) {
            const char* p = buf + mh * HALF + ms * 4096 + arow;
#pragma unroll
            for (int ks = 0; ks < 4; ++ks)
                dst[ms][ks] = *(const bf16x8*)(p + cxk[ks]);
        }
    };
    auto LDB = [&](bf16x8 (&dst)[4], const char* buf, int nh) {
        const char* p = buf + nh * HALF + brow;
#pragma unroll
        for (int ks = 0; ks < 4; ++ks)
            dst[ks] = *(const bf16x8*)(p + cxk[ks]);
    };

    // ---- prologue: stage t0 -> buf0, t1 -> buf1 (16 loads, r5 order) ----
    stageA(lds0, 0, 0);  stageB(lds0, 0, 0);
    stageB(lds0, 1, 0);  stageA(lds0, 1, 0);
    stageA(lds1, 0, BK); stageB(lds1, 0, BK);
    stageB(lds1, 1, BK); stageA(lds1, 1, BK);
    VMCNT(8);            // tile0 fully resident; t1's 8 in flight
    BARRIER();
    LDA(a0, lds0, 0);
    LDB(b0, lds0, 0);

    char* cur = lds0;
    char* nxt = lds1;
    for (int tt = 0; tt < NTILES; ++tt) {
        const int kt2 = (tt + 2) * BK;
        const bool st = (tt < NTILES - 2);
        const bool rd = (tt < NTILES - 1);

        // ---- R1: reads b1<-cur.Bh1 ; MFMA Q(0,0) ----
        LDB(b1, cur, 1);
        MMQ32(a0, b0, 0, 0);
        BARRIER();

        // ---- R2: reads a1<-cur.Ah1 ; stage t+2.{Ah0,Bh0}->cur ; MFMA Q(0,1) ----
        LDA(a1, cur, 1);
        if (st) { stageA(cur, 0, kt2); stageB(cur, 0, kt2); }
        MMQ32(a0, b1, 0, 1);
        // completes t+1.{Ah0,Bh0} (consumed by R3/R4 reads AFTER the barrier)
        if (st) { VMCNT(8); } else { VMCNT(4); }
        BARRIER();

        // ---- R3: reads a0<-nxt.Ah0 ; stage t+2.Bh1->cur ; MFMA Q(1,1) ----
        if (rd) LDA(a0, nxt, 0);
        if (st) stageB(cur, 1, kt2);
        MMQ32(a1, b1, 1, 1);
        BARRIER();

        // ---- R4: stage t+2.Ah1->cur ; MFMA Q(1,0) ; reads b0<-nxt.Bh0 ----
        if (st) stageA(cur, 1, kt2);
        MMQ32(a1, b0, 1, 0);
        if (rd) LDB(b0, nxt, 0);
        // completes t+1.{Bh1,Ah1} (consumed by next R1/R2 after the barrier)
        if (st) { VMCNT(8); } else { VMCNT(0); }
        BARRIER();

        char* tmp = cur; cur = nxt; nxt = tmp;
    }

    // ---- epilogue: scale/bias/clip, fp32 store ----
    // C/D 32x32: col = lane&31, row = (reg&3) + 8*(reg>>2) + 4*(lane>>5)
#pragma unroll
    for (int mh = 0; mh < 2; ++mh)
#pragma unroll
    for (int ms = 0; ms < 2; ++ms)
#pragma unroll
    for (int nh = 0; nh < 2; ++nh) {
        int gc = n0 + nh * 128 + wn * 32 + l31;
        float sc = scale[gc];
        float bi = bias[gc];
        int R0 = m0 + mh * 128 + wm * 64 + ms * 32 + 4 * lh;
#pragma unroll
        for (int r = 0; r < 16; ++r) {
            int row = R0 + (r & 3) + 8 * (r >> 2);
            float val = acc[mh][ms][nh][r] * sc + bi;
            val = fminf(fmaxf(val, -100.0f), 100.0f);
            out[(size_t)row * N_DIM + gc] = val;
        }
    }
}

// ---------------- fallback: fused kernel (ws too small) ----------------
#define FBM 128
#define FBN 128
#define FBK 64

__global__ __launch_bounds__(256)
void ternary_mm_fused(const float* __restrict__ x,
                      const int* __restrict__ pw,
                      const float* __restrict__ scale,
                      const float* __restrict__ bias,
                      float* __restrict__ out)
{
    __shared__ unsigned char As[FBM * FBK * 2];
    __shared__ unsigned char Ws[FBN * FBK * 2];

    const int t    = threadIdx.x;
    const int lane = t & 63;
    const int wave = t >> 6;
    const int wr = wave >> 1;
    const int wc = wave & 1;
    const int lr = lane & 15;
    const int lk = lane >> 4;

    const int n0 = blockIdx.x * FBN;
    const int m0 = blockIdx.y * FBM;

    f32x4 acc[4][4];
#pragma unroll
    for (int m = 0; m < 4; ++m)
#pragma unroll
        for (int n = 0; n < 4; ++n)
            acc[m][n] = (f32x4){0.f, 0.f, 0.f, 0.f};

    for (int kt = 0; kt < K_DIM; kt += FBK) {
#pragma unroll
        for (int p = 0; p < 8; ++p) {
            int idx = p * 256 + t;
            int row = idx >> 4;
            int c4  = idx & 15;
            float4 v = *(const float4*)(x + (size_t)(m0 + row) * K_DIM + kt + c4 * 4);
            ushort4 o;
            o.x = f2bf(v.x); o.y = f2bf(v.y); o.z = f2bf(v.z); o.w = f2bf(v.w);
            int off = (row * 128 + c4 * 8) ^ ((row & 7) << 4);
            *(ushort4*)(As + off) = o;
        }
#pragma unroll
        for (int p = 0; p < 2; ++p) {
            int idx = p * 256 + t;
            int row = idx >> 2;
            int q   = idx & 3;
            int4 v = *(const int4*)(pw + (size_t)(n0 + row) * PW_COLS + (kt >> 2) + q * 4);
            int base = row * 128 + q * 32;
            int xr = (row & 7) << 4;
            int pv[4] = {v.x, v.y, v.z, v.w};
#pragma unroll
            for (int j = 0; j < 4; ++j) {
                ushort4 o;
                o.x = wlut( pv[j]       & 3);
                o.y = wlut((pv[j] >> 2) & 3);
                o.z = wlut((pv[j] >> 4) & 3);
                o.w = wlut((pv[j] >> 6) & 3);
                *(ushort4*)(Ws + ((base + j * 8) ^ xr)) = o;
            }
        }
        __syncthreads();

#pragma unroll
        for (int kk = 0; kk < 2; ++kk) {
            const int cb = kk * 64 + lk * 16;
            bf16x8 af[4], bw[4];
#pragma unroll
            for (int m = 0; m < 4; ++m) {
                int row = wr * 64 + m * 16 + lr;
                af[m] = *(const bf16x8*)(As + ((row * 128 + cb) ^ ((lr & 7) << 4)));
            }
#pragma unroll
            for (int n = 0; n < 4; ++n) {
                int row = wc * 64 + n * 16 + lr;
                bw[n] = *(const bf16x8*)(Ws + ((row * 128 + cb) ^ ((lr & 7) << 4)));
            }
#pragma unroll
            for (int m = 0; m < 4; ++m)
#pragma unroll
                for (int n = 0; n < 4; ++n)
                    acc[m][n] = __builtin_amdgcn_mfma_f32_16x16x32_bf16(
                        af[m], bw[n], acc[m][n], 0, 0, 0);
        }
        __syncthreads();
    }

#pragma unroll
    for (int n = 0; n < 4; ++n) {
        int gcol = n0 + wc * 64 + n * 16 + lr;
        float s = scale[gcol];
        float b = bias[gcol];
#pragma unroll
        for (int m = 0; m < 4; ++m) {
            int growb = m0 + wr * 64 + m * 16 + lk * 4;
#pragma unroll
            for (int r = 0; r < 4; ++r) {
                float v = acc[m][n][r] * s + b;
                v = fminf(fmaxf(v, -100.0f), 100.0f);
                out[(size_t)(growb + r) * N_DIM + gcol] = v;
            }
        }
    }
}

extern "C" void kernel_launch(void* const* d_in, const int* in_sizes, int n_in,
                              void* d_out, int out_size, void* d_ws, size_t ws_size,
                              hipStream_t stream) {
    const float* x     = (const float*)d_in[0];
    const int*   pw    = (const int*)d_in[1];
    const float* scale = (const float*)d_in[2];
    const float* bias  = (const float*)d_in[3];
    float* out = (float*)d_out;

    const size_t xb_bytes = (size_t)M_DIM * K_DIM * 2;
    const size_t wb_bytes = (size_t)N_DIM * K_DIM * 2;
    if (ws_size >= xb_bytes + wb_bytes) {
        unsigned short* xb = (unsigned short*)d_ws;
        unsigned short* wb = (unsigned short*)((char*)d_ws + xb_bytes);

        int n8 = (M_DIM * K_DIM) / 8;
        convert_x_kernel<<<2048, 256, 0, stream>>>(x, xb, n8);
        int n2 = (N_DIM * PW_COLS) / 2;
        unpack_w_kernel<<<2048, 256, 0, stream>>>(pw, wb, n2);

        (void)hipFuncSetAttribute(reinterpret_cast<const void*>(gemm_3232),
                                  hipFuncAttributeMaxDynamicSharedMemorySize,
                                  2 * BUF_BYTES);
        dim3 grid((M_DIM / BM) * (N_DIM / BN));   // 512
        gemm_3232<<<grid, GTHREADS, 2 * BUF_BYTES, stream>>>(xb, wb, scale, bias, out);
    } else {
        dim3 grid(N_DIM / FBN, M_DIM / FBM);
        ternary_mm_fused<<<grid, 256, 0, stream>>>(x, pw, scale, bias, out);
    }
}

// Round 13
// 251.116 us; speedup vs baseline: 2.5313x; 1.2165x over previous
//
#include <hip/hip_runtime.h>
#include <hip/hip_bf16.h>

#define K_DIM 4096
#define N_DIM 4096
#define M_DIM 8192
#define PW_COLS 1024  // K_DIM/4

typedef __attribute__((ext_vector_type(4))) float f32x4;
typedef __attribute__((ext_vector_type(8))) short bf16x8;
typedef __attribute__((address_space(3))) void lds_void_t;
typedef __attribute__((address_space(1))) const void glb_void_t;

__device__ __forceinline__ unsigned short f2bf(float f) {
    unsigned int u = __float_as_uint(f);
    u += 0x7FFF + ((u >> 16) & 1);   // round-to-nearest-even
    return (unsigned short)(u >> 16);
}

// ternary code {0,1,2,3} -> bf16 bits of {-1,0,1,2}
__device__ __forceinline__ unsigned short wlut(int tt) {
    return (unsigned short)(0x40003F800000BF80ULL >> (tt << 4));
}

// ---------------- pre-pass 1: x fp32 -> bf16 ----------------
__global__ __launch_bounds__(256)
void convert_x_kernel(const float* __restrict__ x, unsigned short* __restrict__ xb, int n8)
{
    int stride = gridDim.x * blockDim.x;
    for (int i = blockIdx.x * blockDim.x + threadIdx.x; i < n8; i += stride) {
        float4 v0 = *(const float4*)(x + (size_t)i * 8);
        float4 v1 = *(const float4*)(x + (size_t)i * 8 + 4);
        ushort4 o0, o1;
        o0.x = f2bf(v0.x); o0.y = f2bf(v0.y); o0.z = f2bf(v0.z); o0.w = f2bf(v0.w);
        o1.x = f2bf(v1.x); o1.y = f2bf(v1.y); o1.z = f2bf(v1.z); o1.w = f2bf(v1.w);
        *(ushort4*)(xb + (size_t)i * 8) = o0;
        *(ushort4*)(xb + (size_t)i * 8 + 4) = o1;
    }
}

// ---------------- pre-pass 2: pw -> bf16 W [N][K] ----------------
__global__ __launch_bounds__(256)
void unpack_w_kernel(const int* __restrict__ pw, unsigned short* __restrict__ wb, int n2)
{
    int stride = gridDim.x * blockDim.x;
    for (int i = blockIdx.x * blockDim.x + threadIdx.x; i < n2; i += stride) {
        int2 p = *(const int2*)(pw + (size_t)i * 2);
        ushort4 a, b;
        a.x = wlut( p.x       & 3);
        a.y = wlut((p.x >> 2) & 3);
        a.z = wlut((p.x >> 4) & 3);
        a.w = wlut((p.x >> 6) & 3);
        b.x = wlut( p.y       & 3);
        b.y = wlut((p.y >> 2) & 3);
        b.z = wlut((p.y >> 4) & 3);
        b.w = wlut((p.y >> 6) & 3);
        *(ushort4*)(wb + (size_t)i * 8) = a;
        *(ushort4*)(wb + (size_t)i * 8 + 4) = b;
    }
}

// ---------------- main GEMM: 256x256, 2 barriers/K-tile (merged r5 regions) ----------------
#define BM 256
#define BN 256
#define BK 64
#define GTHREADS 512
#define BUF_BYTES 65536   // A 32K + B 32K
#define B_TILE 32768
#define HALF 16384
#define NTILES 64         // K_DIM / BK

#define BARRIER() asm volatile("s_barrier" ::: "memory")
#define VMCNT(N)  asm volatile("s_waitcnt vmcnt(" #N ")" ::: "memory")
// 1-barrier WAR guard: each wave drains its own LDS reads before arriving at
// the barrier; any wave's post-barrier DMA therefore cannot overwrite them.
#define LGKM0()   asm volatile("s_waitcnt lgkmcnt(0)" ::: "memory")

// MFMA quadrant: 16 MFMAs, kk-outer (8 independent per kk; acc dep distance 8)
#define MMQ(Aarr, Barr, MH, NH) do { \
    __builtin_amdgcn_s_setprio(1); \
    _Pragma("unroll") \
    for (int kk = 0; kk < 2; ++kk) { \
      _Pragma("unroll") \
      for (int im = 0; im < 4; ++im) { \
        _Pragma("unroll") \
        for (int jn = 0; jn < 2; ++jn) { \
          acc[MH][im][NH][jn] = __builtin_amdgcn_mfma_f32_16x16x32_bf16( \
              Aarr[im][kk], Barr[jn][kk], acc[MH][im][NH][jn], 0, 0, 0); \
        } \
      } \
    } \
    __builtin_amdgcn_s_setprio(0); \
} while (0)

__global__ __launch_bounds__(GTHREADS, 2)
void gemm_2b(const unsigned short* __restrict__ A,   // [M][K] bf16
             const unsigned short* __restrict__ B,   // [N][K] bf16
             const float* __restrict__ scale,
             const float* __restrict__ bias,
             float* __restrict__ out)
{
    extern __shared__ __align__(16) char smem[];

    const int t    = threadIdx.x;
    const int lane = t & 63;
    const int wave = t >> 6;
    const int wm = wave >> 2;      // 0..1  (M group)
    const int wn = wave & 3;       // 0..3  (N group)
    const int lr = lane & 15;
    const int lk = lane >> 4;      // 0..3

    // bijective XCD swizzle: 512 blocks, 8 XCDs, 64 per chunk
    int bid = blockIdx.x;
    int swz = (bid & 7) * 64 + (bid >> 3);
    const int m0 = (swz >> 4) * BM;   // 32 m-blocks
    const int n0 = (swz & 15) * BN;   // 16 n-blocks

    // ---- staging addresses (pre-swizzled global source, linear LDS dest) ----
    const int l8 = lane >> 3;                 // 0..7  (row within 8-row chunk)
    const int lc = ((lane & 7) ^ l8) * 8;     // inverse-swizzled col (elems)
    const unsigned short* aS = A + (size_t)(m0 + wave * 16 + l8) * K_DIM + lc;
    const unsigned short* bS = B + (size_t)(n0 + wave * 16 + l8) * K_DIM + lc;
    char* const lds0 = smem;
    char* const lds1 = smem + BUF_BYTES;
    const int chunkoff = wave * 2048;         // 2 chunks x 1024B per wave

    auto stageA = [&](char* buf, int h, int kt) {
        const unsigned short* s0 = aS + (size_t)(h * 128) * K_DIM + kt;
        char* d0 = buf + h * HALF + chunkoff;
        __builtin_amdgcn_global_load_lds((glb_void_t*)s0,
            (lds_void_t*)(void*)d0, 16, 0, 0);
        __builtin_amdgcn_global_load_lds((glb_void_t*)(s0 + 8 * K_DIM),
            (lds_void_t*)(void*)(d0 + 1024), 16, 0, 0);
    };
    auto stageB = [&](char* buf, int h, int kt) {
        const unsigned short* s0 = bS + (size_t)(h * 128) * K_DIM + kt;
        char* d0 = buf + B_TILE + h * HALF + chunkoff;
        __builtin_amdgcn_global_load_lds((glb_void_t*)s0,
            (lds_void_t*)(void*)d0, 16, 0, 0);
        __builtin_amdgcn_global_load_lds((glb_void_t*)(s0 + 8 * K_DIM),
            (lds_void_t*)(void*)(d0 + 1024), 16, 0, 0);
    };

    // ---- fragment-read offsets (swizzled, r5-verified: 0 conflicts) ----
    const int swzc = (lr & 7) << 4;
    const int cx0 = (lk * 16) ^ swzc;         // kk=0 col bytes, swizzled
    const int cx1 = (64 + lk * 16) ^ swzc;    // kk=1
    const int arow = (wm * 64 + lr) * 128;
    const int brow = (wn * 32 + lr) * 128 + B_TILE;

    f32x4 acc[2][4][2][2] = {};   // [mh][im][nh][jn]
    bf16x8 a0[4][2], a1[4][2];    // A-half fragments [im][kk]
    bf16x8 b0[2][2], b1[2][2];    // B-half fragments [jn][kk]

    auto LDA = [&](bf16x8 (&dst)[4][2], const char* buf, int mh) {
#pragma unroll
        for (int im = 0; im < 4; ++im) {
            const char* p = buf + arow + mh * HALF + im * 2048;
            dst[im][0] = *(const bf16x8*)(p + cx0);
            dst[im][1] = *(const bf16x8*)(p + cx1);
        }
    };
    auto LDB = [&](bf16x8 (&dst)[2][2], const char* buf, int nh) {
#pragma unroll
        for (int jn = 0; jn < 2; ++jn) {
            const char* p = buf + brow + nh * HALF + jn * 2048;
            dst[jn][0] = *(const bf16x8*)(p + cx0);
            dst[jn][1] = *(const bf16x8*)(p + cx1);
        }
    };

    // ---- prologue: stage t0 -> buf0, t1 -> buf1 (FIFO order = steady state) ----
    stageA(lds0, 0, 0);  stageB(lds0, 0, 0);
    stageB(lds0, 1, 0);  stageA(lds0, 1, 0);
    stageA(lds1, 0, BK); stageB(lds1, 0, BK);
    stageB(lds1, 1, BK); stageA(lds1, 1, BK);
    VMCNT(8);            // tile0 fully resident; t1's 8 loads in flight
    BARRIER();
    LDA(a0, lds0, 0);    // preread tile0 Q(0,0) operands
    LDB(b0, lds0, 0);
    LGKM0();             // prereads drain before iter0 can stage into lds0
    BARRIER();

    char* cur = lds0;
    char* nxt = lds1;
    for (int tt = 0; tt < NTILES; ++tt) {
        const int kt2 = (tt + 2) * BK;
        const bool st = (tt < NTILES - 2);
        const bool rd = (tt < NTILES - 1);

        // ---- R12: reads b1,a1<-cur ; stage t+2.{Ah0,Bh0}->cur ; MFMA Q00,Q01 ----
        LDB(b1, cur, 1);                     // 4 ds_read_b128
        LDA(a1, cur, 1);                     // 8
        if (st) { stageA(cur, 0, kt2); stageB(cur, 0, kt2); }   // 4 vmem
        MMQ(a0, b0, 0, 0);
        MMQ(a0, b1, 0, 1);                   // waits (counted lgkm) on b1 only
        // retire (t+1).{Ah0,Bh0} — consumed by R34's nxt-reads after barrier
        if (st) { VMCNT(8); } else { VMCNT(4); }
        LGKM0();
        BARRIER();

        // ---- R34: read a0<-nxt ; stage t+2.{Bh1,Ah1}->cur ; MFMA Q11,Q10 ; read b0<-nxt ----
        if (rd) LDA(a0, nxt, 0);             // 8 (a0 last used in R12 ✓)
        if (st) { stageB(cur, 1, kt2); stageA(cur, 1, kt2); }   // 4 vmem
        MMQ(a1, b1, 1, 1);
        MMQ(a1, b0, 1, 0);                   // uses OLD b0
        if (rd) LDB(b0, nxt, 0);             // 4 (after last use of old b0)
        // retire (t+1).{Bh1,Ah1} — consumed by next R12's cur-reads after barrier
        if (st) { VMCNT(8); } else { VMCNT(0); }
        LGKM0();
        BARRIER();

        char* tmp = cur; cur = nxt; nxt = tmp;
    }

    // ---- epilogue: scale/bias/clip, fp32 store ----
#pragma unroll
    for (int mh = 0; mh < 2; ++mh)
#pragma unroll
    for (int nh = 0; nh < 2; ++nh)
#pragma unroll
    for (int jn = 0; jn < 2; ++jn) {
        int gc = n0 + nh * 128 + wn * 32 + jn * 16 + lr;
        float sc = scale[gc];
        float bi = bias[gc];
#pragma unroll
        for (int im = 0; im < 4; ++im) {
            int gr = m0 + mh * 128 + wm * 64 + im * 16 + lk * 4;
#pragma unroll
            for (int v = 0; v < 4; ++v) {
                float val = acc[mh][im][nh][jn][v] * sc + bi;
                val = fminf(fmaxf(val, -100.0f), 100.0f);
                out[(size_t)(gr + v) * N_DIM + gc] = val;
            }
        }
    }
}

// ---------------- fallback: fused kernel (ws too small) ----------------
#define FBM 128
#define FBN 128
#define FBK 64

__global__ __launch_bounds__(256)
void ternary_mm_fused(const float* __restrict__ x,
                      const int* __restrict__ pw,
                      const float* __restrict__ scale,
                      const float* __restrict__ bias,
                      float* __restrict__ out)
{
    __shared__ unsigned char As[FBM * FBK * 2];
    __shared__ unsigned char Ws[FBN * FBK * 2];

    const int t    = threadIdx.x;
    const int lane = t & 63;
    const int wave = t >> 6;
    const int wr = wave >> 1;
    const int wc = wave & 1;
    const int lr = lane & 15;
    const int lk = lane >> 4;

    const int n0 = blockIdx.x * FBN;
    const int m0 = blockIdx.y * FBM;

    f32x4 acc[4][4];
#pragma unroll
    for (int m = 0; m < 4; ++m)
#pragma unroll
        for (int n = 0; n < 4; ++n)
            acc[m][n] = (f32x4){0.f, 0.f, 0.f, 0.f};

    for (int kt = 0; kt < K_DIM; kt += FBK) {
#pragma unroll
        for (int p = 0; p < 8; ++p) {
            int idx = p * 256 + t;
            int row = idx >> 4;
            int c4  = idx & 15;
            float4 v = *(const float4*)(x + (size_t)(m0 + row) * K_DIM + kt + c4 * 4);
            ushort4 o;
            o.x = f2bf(v.x); o.y = f2bf(v.y); o.z = f2bf(v.z); o.w = f2bf(v.w);
            int off = (row * 128 + c4 * 8) ^ ((row & 7) << 4);
            *(ushort4*)(As + off) = o;
        }
#pragma unroll
        for (int p = 0; p < 2; ++p) {
            int idx = p * 256 + t;
            int row = idx >> 2;
            int q   = idx & 3;
            int4 v = *(const int4*)(pw + (size_t)(n0 + row) * PW_COLS + (kt >> 2) + q * 4);
            int base = row * 128 + q * 32;
            int xr = (row & 7) << 4;
            int pv[4] = {v.x, v.y, v.z, v.w};
#pragma unroll
            for (int j = 0; j < 4; ++j) {
                ushort4 o;
                o.x = wlut( pv[j]       & 3);
                o.y = wlut((pv[j] >> 2) & 3);
                o.z = wlut((pv[j] >> 4) & 3);
                o.w = wlut((pv[j] >> 6) & 3);
                *(ushort4*)(Ws + ((base + j * 8) ^ xr)) = o;
            }
        }
        __syncthreads();

#pragma unroll
        for (int kk = 0; kk < 2; ++kk) {
            const int cb = kk * 64 + lk * 16;
            bf16x8 af[4], bw[4];
#pragma unroll
            for (int m = 0; m < 4; ++m) {
                int row = wr * 64 + m * 16 + lr;
                af[m] = *(const bf16x8*)(As + ((row * 128 + cb) ^ ((lr & 7) << 4)));
            }
#pragma unroll
            for (int n = 0; n < 4; ++n) {
                int row = wc * 64 + n * 16 + lr;
                bw[n] = *(const bf16x8*)(Ws + ((row * 128 + cb) ^ ((lr & 7) << 4)));
            }
#pragma unroll
            for (int m = 0; m < 4; ++m)
#pragma unroll
                for (int n = 0; n < 4; ++n)
                    acc[m][n] = __builtin_amdgcn_mfma_f32_16x16x32_bf16(
                        af[m], bw[n], acc[m][n], 0, 0, 0);
        }
        __syncthreads();
    }

#pragma unroll
    for (int n = 0; n < 4; ++n) {
        int gcol = n0 + wc * 64 + n * 16 + lr;
        float s = scale[gcol];
        float b = bias[gcol];
#pragma unroll
        for (int m = 0; m < 4; ++m) {
            int growb = m0 + wr * 64 + m * 16 + lk * 4;
#pragma unroll
            for (int r = 0; r < 4; ++r) {
                float v = acc[m][n][r] * s + b;
                v = fminf(fmaxf(v, -100.0f), 100.0f);
                out[(size_t)(growb + r) * N_DIM + gcol] = v;
            }
        }
    }
}

extern "C" void kernel_launch(void* const* d_in, const int* in_sizes, int n_in,
                              void* d_out, int out_size, void* d_ws, size_t ws_size,
                              hipStream_t stream) {
    const float* x     = (const float*)d_in[0];
    const int*   pw    = (const int*)d_in[1];
    const float* scale = (const float*)d_in[2];
    const float* bias  = (const float*)d_in[3];
    float* out = (float*)d_out;

    const size_t xb_bytes = (size_t)M_DIM * K_DIM * 2;
    const size_t wb_bytes = (size_t)N_DIM * K_DIM * 2;
    if (ws_size >= xb_bytes + wb_bytes) {
        unsigned short* xb = (unsigned short*)d_ws;
        unsigned short* wb = (unsigned short*)((char*)d_ws + xb_bytes);

        int n8 = (M_DIM * K_DIM) / 8;
        convert_x_kernel<<<2048, 256, 0, stream>>>(x, xb, n8);
        int n2 = (N_DIM * PW_COLS) / 2;
        unpack_w_kernel<<<2048, 256, 0, stream>>>(pw, wb, n2);

        (void)hipFuncSetAttribute(reinterpret_cast<const void*>(gemm_2b),
                                  hipFuncAttributeMaxDynamicSharedMemorySize,
                                  2 * BUF_BYTES);
        dim3 grid((M_DIM / BM) * (N_DIM / BN));   // 512
        gemm_2b<<<grid, GTHREADS, 2 * BUF_BYTES, stream>>>(xb, wb, scale, bias, out);
    } else {
        dim3 grid(N_DIM / FBN, M_DIM / FBM);
        ternary_mm_fused<<<grid, 256, 0, stream>>>(x, pw, scale, bias, out);
    }
}